// Round 1
// baseline (833.129 us; speedup 1.0000x reference)
//
#include <hip/hip_runtime.h>
#include <math.h>

// Problem constants (fixed by reference setup_inputs)
#define BB 32
#define TT 512
#define DD 384
#define TI 16   // output rows per block

__global__ __launch_bounds__(256, 4)
void gauss_upsample_kernel(const float* __restrict__ feats,
                           const float* __restrict__ rng,
                           const int*   __restrict__ dur,
                           float* __restrict__ out,
                           int O)
{
    __shared__ float sC[TT];      // gaussian centers c[t]
    __shared__ float sInvR[TT];   // 1/(rng+1e-6)
    __shared__ float sW[TI][TT];  // unnormalized weights per output row
    __shared__ float sInvSum[TI];
    __shared__ int   sTot[8];
    __shared__ int   sOffs[8];

    const int tid  = threadIdx.x;
    const int lane = tid & 63;
    const int wave = tid >> 6;
    const int b    = blockIdx.y;
    const int i0   = blockIdx.x * TI;

    // ---- Phase 0: inclusive cumsum of durations -> centers; stage 1/r ----
    const int t0 = tid, t1 = tid + 256;
    int dv0 = dur[b * TT + t0];
    int dv1 = dur[b * TT + t1];
    int v0 = dv0, v1 = dv1;
    #pragma unroll
    for (int off = 1; off < 64; off <<= 1) {
        int n0 = __shfl_up(v0, off);
        int n1 = __shfl_up(v1, off);
        if (lane >= off) { v0 += n0; v1 += n1; }
    }
    if (lane == 63) { sTot[wave] = v0; sTot[wave + 4] = v1; }
    __syncthreads();
    if (tid == 0) {
        int run = 0;
        #pragma unroll
        for (int k = 0; k < 8; ++k) { sOffs[k] = run; run += sTot[k]; }
    }
    __syncthreads();
    {
        // inclusive cumsum: within-chunk scan + chunk offset
        float cum0 = (float)(v0 + sOffs[t0 >> 6]);
        float cum1 = (float)(v1 + sOffs[t1 >> 6]);
        sC[t0] = 0.5f * (float)dv0 + cum0;
        sC[t1] = 0.5f * (float)dv1 + cum1;
        float r0 = rng[b * TT + t0] + 1e-6f;
        float r1 = rng[b * TT + t1] + 1e-6f;
        sInvR[t0] = 1.0f / r0;
        sInvR[t1] = 1.0f / r1;
    }
    __syncthreads();

    // ---- Phase 1: unnormalized weights + row sums (4 waves x 4 rows) ----
    const float INV_R2PI = 0.3989422804014327f;  // 1/sqrt(2*pi)
    #pragma unroll
    for (int rr = 0; rr < 4; ++rr) {
        int i = wave * 4 + rr;
        float time = (float)(i0 + i);
        float s = 0.0f;
        #pragma unroll
        for (int k = 0; k < 8; ++k) {
            int t = lane + 64 * k;
            float invr = sInvR[t];
            float z = (time - sC[t]) * invr;
            float w = __expf(-0.5f * z * z) * (invr * INV_R2PI) + 1e-6f;
            sW[i][t] = w;
            s += w;
        }
        #pragma unroll
        for (int off = 32; off >= 1; off >>= 1)
            s += __shfl_xor(s, off);
        if (lane == 0) sInvSum[i] = 1.0f / s;
    }
    __syncthreads();

    // ---- Phase 2: out[i, d] = (1/sum_i) * sum_t w[i][t] * feats[t, d] ----
    const float* featsB = feats + (size_t)b * TT * DD;
    float acc0[TI], acc1[TI];
    #pragma unroll
    for (int i = 0; i < TI; ++i) { acc0[i] = 0.0f; acc1[i] = 0.0f; }

    const bool two = (tid < 128);      // wave-uniform: waves 0,1 own 2 columns
    const int d0 = tid;                // columns 0..255
    const int d1 = 256 + tid;          // columns 256..383 (tid<128 only)
    const float4* wv = reinterpret_cast<const float4*>(&sW[0][0]);

    for (int t4 = 0; t4 < TT / 4; ++t4) {
        float f0[4], f1[4];
        const float* p = featsB + (t4 * 4) * DD + d0;
        #pragma unroll
        for (int j = 0; j < 4; ++j) f0[j] = p[j * DD];
        if (two) {
            #pragma unroll
            for (int j = 0; j < 4; ++j) f1[j] = p[256 + j * DD];
        }
        #pragma unroll
        for (int i = 0; i < TI; ++i) {
            float4 w4 = wv[i * (TT / 4) + t4];
            acc0[i] = fmaf(w4.x, f0[0], acc0[i]);
            acc0[i] = fmaf(w4.y, f0[1], acc0[i]);
            acc0[i] = fmaf(w4.z, f0[2], acc0[i]);
            acc0[i] = fmaf(w4.w, f0[3], acc0[i]);
            if (two) {
                acc1[i] = fmaf(w4.x, f1[0], acc1[i]);
                acc1[i] = fmaf(w4.y, f1[1], acc1[i]);
                acc1[i] = fmaf(w4.z, f1[2], acc1[i]);
                acc1[i] = fmaf(w4.w, f1[3], acc1[i]);
            }
        }
    }

    // ---- Epilogue: normalize and store ----
    #pragma unroll
    for (int i = 0; i < TI; ++i) {
        int ig = i0 + i;
        if (ig < O) {
            float inv = sInvSum[i];
            out[((size_t)b * O + ig) * DD + d0] = acc0[i] * inv;
            if (two)
                out[((size_t)b * O + ig) * DD + d1] = acc1[i] * inv;
        }
    }
}

extern "C" void kernel_launch(void* const* d_in, const int* in_sizes, int n_in,
                              void* d_out, int out_size, void* d_ws, size_t ws_size,
                              hipStream_t stream) {
    const float* feats = (const float*)d_in[0];
    const float* rng   = (const float*)d_in[1];
    const int*   dur   = (const int*)d_in[2];
    float* out = (float*)d_out;

    const int O = out_size / (BB * DD);   // outlen
    dim3 grid((O + TI - 1) / TI, BB);
    gauss_upsample_kernel<<<grid, 256, 0, stream>>>(feats, rng, dur, out, O);
}

// Round 2
// 215.395 us; speedup vs baseline: 3.8679x; 3.8679x over previous
//
#include <hip/hip_runtime.h>
#include <math.h>

// Problem constants (fixed by reference setup_inputs)
#define BB 32
#define TT 512
#define DD 384
#define ROWS 48          // output rows per block (main kernel)
#define TW 520           // sW row stride in bf16 elems: 1040 B -> 4-bank step, balanced b128
#define R2PI_INV 0.3989422804014327f

typedef short bf16x8 __attribute__((ext_vector_type(8)));
typedef float f32x4  __attribute__((ext_vector_type(4)));

__device__ __forceinline__ ushort f2bf(float f) {
    // round-to-nearest-even fp32 -> bf16 (inputs here are finite, positive)
    unsigned u = __float_as_uint(f);
    u += 0x7fffu + ((u >> 16) & 1u);
    return (ushort)(u >> 16);
}

// ---- Kernel A: per-batch duration cumsum -> gaussian centers + 1/(rng+eps) ----
__global__ __launch_bounds__(256)
void prep_kernel(const float* __restrict__ rng,
                 const int*   __restrict__ dur,
                 float* __restrict__ cOut,
                 float* __restrict__ irOut)
{
    __shared__ int sTot[8];
    __shared__ int sOffs[8];
    const int tid = threadIdx.x, lane = tid & 63, wave = tid >> 6;
    const int b = blockIdx.x;
    const int t0 = tid, t1 = tid + 256;
    int dv0 = dur[b * TT + t0];
    int dv1 = dur[b * TT + t1];
    int v0 = dv0, v1 = dv1;
    #pragma unroll
    for (int off = 1; off < 64; off <<= 1) {
        int n0 = __shfl_up(v0, off);
        int n1 = __shfl_up(v1, off);
        if (lane >= off) { v0 += n0; v1 += n1; }
    }
    if (lane == 63) { sTot[wave] = v0; sTot[wave + 4] = v1; }
    __syncthreads();
    if (tid == 0) {
        int run = 0;
        #pragma unroll
        for (int k = 0; k < 8; ++k) { sOffs[k] = run; run += sTot[k]; }
    }
    __syncthreads();
    cOut[b * TT + t0] = 0.5f * (float)dv0 + (float)(v0 + sOffs[t0 >> 6]);
    cOut[b * TT + t1] = 0.5f * (float)dv1 + (float)(v1 + sOffs[t1 >> 6]);
    irOut[b * TT + t0] = 1.0f / (rng[b * TT + t0] + 1e-6f);
    irOut[b * TT + t1] = 1.0f / (rng[b * TT + t1] + 1e-6f);
}

// ---- Kernel B: feats [B][T][D] fp32 -> featsT [B][D][T] bf16 ----
__global__ __launch_bounds__(256)
void transpose_kernel(const float* __restrict__ feats,
                      ushort* __restrict__ featsT)
{
    __shared__ ushort sT[64][65];   // +1 ushort pad
    const int tid = threadIdx.x;
    const int t0 = blockIdx.x * 64, d0 = blockIdx.y * 64, b = blockIdx.z;

    const float* src = feats + ((size_t)b * TT + t0) * DD + d0;
    #pragma unroll
    for (int it = 0; it < 16; ++it) {
        int idx = it * 256 + tid;
        int t = idx >> 6, d = idx & 63;
        sT[t][d] = f2bf(src[(size_t)t * DD + d]);
    }
    __syncthreads();
    unsigned* dst = (unsigned*)(featsT + ((size_t)b * DD + d0) * TT + t0);
    #pragma unroll
    for (int it = 0; it < 8; ++it) {
        int idx = it * 256 + tid;
        int d = idx >> 5, tp = idx & 31;
        unsigned lo = sT[2 * tp][d];
        unsigned hi = sT[2 * tp + 1][d];
        dst[(size_t)d * (TT / 2) + tp] = lo | (hi << 16);
    }
}

// ---- Kernel C: generate W tile (bf16, unnormalized) + MFMA GEMM + scaled store ----
__global__ __launch_bounds__(256, 2)
void gemm_kernel(const ushort* __restrict__ featsT,
                 const float*  __restrict__ cW,
                 const float*  __restrict__ irW,
                 float* __restrict__ out, int O)
{
    __shared__ ushort sW[ROWS * TW];   // 48*520*2 = 49,920 B
    __shared__ float  sInvSum[ROWS];

    const int tid = threadIdx.x;
    const int ln  = tid & 63;
    const int wv  = tid >> 6;
    const int qd  = ln >> 4;     // quad 0..3
    const int lm  = ln & 15;
    const int b   = blockIdx.y;
    const int i0  = blockIdx.x * ROWS;

    // ---- Phase 1: W rows in bf16 (unnormalized) + fp32 row sums ----
    // lane ln owns t = 8*ln .. 8*ln+7 for every row
    float c8[8], ir8[8];
    {
        const float4* cB = (const float4*)(cW + b * TT);
        const float4* iB = (const float4*)(irW + b * TT);
        float4 ca = cB[2 * ln], cb = cB[2 * ln + 1];
        float4 ia = iB[2 * ln], ib = iB[2 * ln + 1];
        c8[0] = ca.x; c8[1] = ca.y; c8[2] = ca.z; c8[3] = ca.w;
        c8[4] = cb.x; c8[5] = cb.y; c8[6] = cb.z; c8[7] = cb.w;
        ir8[0] = ia.x; ir8[1] = ia.y; ir8[2] = ia.z; ir8[3] = ia.w;
        ir8[4] = ib.x; ir8[5] = ib.y; ir8[6] = ib.z; ir8[7] = ib.w;
    }
    #pragma unroll
    for (int rr = 0; rr < ROWS / 4; ++rr) {     // 12 rows per wave
        int row = wv * (ROWS / 4) + rr;
        float time = (float)(i0 + row);
        float s = 0.0f;
        ushort h[8];
        #pragma unroll
        for (int j = 0; j < 8; ++j) {
            float z = (time - c8[j]) * ir8[j];
            float w = __expf(-0.5f * z * z) * ir8[j] * R2PI_INV + 1e-6f;
            s += w;
            h[j] = f2bf(w);
        }
        uint4 pk;
        pk.x = (unsigned)h[0] | ((unsigned)h[1] << 16);
        pk.y = (unsigned)h[2] | ((unsigned)h[3] << 16);
        pk.z = (unsigned)h[4] | ((unsigned)h[5] << 16);
        pk.w = (unsigned)h[6] | ((unsigned)h[7] << 16);
        *(uint4*)&sW[row * TW + 8 * ln] = pk;
        #pragma unroll
        for (int off = 32; off >= 1; off >>= 1) s += __shfl_xor(s, off);
        if (ln == 0) sInvSum[row] = 1.0f / s;
    }
    __syncthreads();

    // ---- Phase 2: MFMA. Waves split N (96 cols each); B-frags straight from L2 ----
    f32x4 acc[3][6];
    #pragma unroll
    for (int r = 0; r < 3; ++r)
        #pragma unroll
        for (int nt = 0; nt < 6; ++nt)
            acc[r][nt] = (f32x4){0.f, 0.f, 0.f, 0.f};

    const int colbase = wv * 96 + lm;
    const ushort* bp = featsT + ((size_t)b * DD + colbase) * TT + qd * 8;

    bf16x8 Bc[6], Bn[6];
    #pragma unroll
    for (int nt = 0; nt < 6; ++nt)
        Bc[nt] = *(const bf16x8*)(bp + (size_t)nt * 16 * TT);

    for (int ks = 0; ks < 16; ++ks) {
        const int ko = ks * 32;
        if (ks < 15) {
            #pragma unroll
            for (int nt = 0; nt < 6; ++nt)
                Bn[nt] = *(const bf16x8*)(bp + (size_t)nt * 16 * TT + ko + 32);
        }
        #pragma unroll
        for (int r = 0; r < 3; ++r) {
            bf16x8 A = *(const bf16x8*)&sW[(r * 16 + lm) * TW + ko + qd * 8];
            #pragma unroll
            for (int nt = 0; nt < 6; ++nt)
                acc[r][nt] = __builtin_amdgcn_mfma_f32_16x16x32_bf16(A, Bc[nt], acc[r][nt], 0, 0, 0);
        }
        if (ks < 15) {
            #pragma unroll
            for (int nt = 0; nt < 6; ++nt) Bc[nt] = Bn[nt];
        }
    }

    // ---- Epilogue: scale by 1/rowsum, store. C/D: col=lm, row=qd*4+reg ----
    #pragma unroll
    for (int r = 0; r < 3; ++r) {
        #pragma unroll
        for (int reg = 0; reg < 4; ++reg) {
            int lrow = r * 16 + qd * 4 + reg;
            int grow = i0 + lrow;
            if (grow < O) {
                float sc = sInvSum[lrow];
                float* op = out + ((size_t)b * O + grow) * DD + wv * 96 + lm;
                #pragma unroll
                for (int nt = 0; nt < 6; ++nt)
                    op[nt * 16] = acc[r][nt][reg] * sc;
            }
        }
    }
}

extern "C" void kernel_launch(void* const* d_in, const int* in_sizes, int n_in,
                              void* d_out, int out_size, void* d_ws, size_t ws_size,
                              hipStream_t stream) {
    const float* feats = (const float*)d_in[0];
    const float* rng   = (const float*)d_in[1];
    const int*   dur   = (const int*)d_in[2];
    float* out = (float*)d_out;
    const int O = out_size / (BB * DD);

    // workspace layout: featsT bf16 [B][D][T] | centers [B][T] f32 | invr [B][T] f32
    ushort* featsT = (ushort*)d_ws;
    float*  cW  = (float*)((char*)d_ws + (size_t)BB * DD * TT * 2);
    float*  irW = cW + BB * TT;

    prep_kernel<<<BB, 256, 0, stream>>>(rng, dur, cW, irW);
    dim3 tg(TT / 64, DD / 64, BB);
    transpose_kernel<<<tg, 256, 0, stream>>>(feats, featsT);
    dim3 gg((O + ROWS - 1) / ROWS, BB);
    gemm_kernel<<<gg, 256, 0, stream>>>(featsT, cW, irW, out, O);
}